// Round 3
// baseline (206.374 us; speedup 1.0000x reference)
//
#include <hip/hip_runtime.h>
#include <hip/hip_fp16.h>
#include <cmath>

namespace {

typedef float    vf2 __attribute__((ext_vector_type(2)));
typedef float    vf4 __attribute__((ext_vector_type(4)));
typedef unsigned uv2 __attribute__((ext_vector_type(2)));

constexpr int kN = 524288;      // points (== 1<<19, same as kCap — convenient)
constexpr int kL = 16;          // levels
constexpr int kCapLog2 = 19;
constexpr int kCap = 1 << kCapLog2;
constexpr int kCapMask = kCap - 1;
constexpr unsigned kHashMult = 2531011u;

struct ScaleArr { float s[kL]; };

// ---------------- shared per-thread math (identical numerics to R1) --------
__device__ __forceinline__ void permuto_point(
    float x0, float x1, float x2, int rem0[4], int rank[4], float w[4])
{
    const float E00 = (float)( 0.70710678118654752440);
    const float E01 = (float)( 0.40824829046386301637);
    const float E02 = (float)( 0.28867513459481288225);
    const float E10 = (float)(-0.70710678118654752440);
    const float E21 = (float)(-2.0 * 0.40824829046386301637);
    const float E32 = (float)(-3.0 * 0.28867513459481288225);

    float elev[4];
    elev[0] = E00 * x0 + E01 * x1 + E02 * x2;
    elev[1] = E10 * x0 + E01 * x1 + E02 * x2;
    elev[2] =            E21 * x1 + E02 * x2;
    elev[3] =                       E32 * x2;

    float rem0f[4], di[4];
    #pragma unroll
    for (int v = 0; v < 4; ++v) {
        rem0f[v] = rintf(elev[v] * 0.25f) * 4.0f;
        di[v]    = elev[v] - rem0f[v];
    }
    const int sums = (int)((((rem0f[0] + rem0f[1]) + rem0f[2]) + rem0f[3]) * 0.25f);

    #pragma unroll
    for (int a = 0; a < 4; ++a) {
        int r = 0;
        #pragma unroll
        for (int b = 0; b < 4; ++b)
            r += (di[b] > di[a]) || (di[b] == di[a] && b < a);
        rank[a] = r + sums;
        rem0[a] = (int)rem0f[a];
    }
    #pragma unroll
    for (int v = 0; v < 4; ++v) {
        if (rank[v] < 0)      { rank[v] += 4; rem0[v] += 4; }
        else if (rank[v] > 3) { rank[v] -= 4; rem0[v] -= 4; }
    }

    float dbr[4];
    #pragma unroll
    for (int v = 0; v < 4; ++v)
        dbr[rank[v] & 3] = (elev[v] - (float)rem0[v]) * 0.25f;

    w[0] = (1.0f + dbr[3]) - dbr[0];
    w[1] = dbr[2] - dbr[3];
    w[2] = dbr[1] - dbr[2];
    w[3] = dbr[0] - dbr[1];
}

// ---------------- kernel 1: f32 params -> fp16 table in ws -----------------
__global__ __launch_bounds__(256) void conv_tab(const float* __restrict__ params,
                                                unsigned* __restrict__ tab)
{
    const int i = blockIdx.x * 256 + threadIdx.x;   // one float4 -> one 8B half4
    vf4 v = __builtin_nontemporal_load((const vf4*)params + i);
    __half2 a = __floats2half2_rn(v.x, v.y);
    __half2 b = __floats2half2_rn(v.z, v.w);
    uv2 o;
    o.x = *reinterpret_cast<unsigned*>(&a);
    o.y = *reinterpret_cast<unsigned*>(&b);
    __builtin_nontemporal_store(o, (uv2*)tab + i);
}

// ------- kernel 2: 2 levels/thread ({xcd, xcd+8}), 8-way gather MLP --------
__global__ __launch_bounds__(256) void permuto_main2(
    const float* __restrict__ pos,
    const unsigned* __restrict__ tab,   // half2 per table entry
    vf2* __restrict__ out_t,            // [level][point]
    ScaleArr sc)
{
    const int b   = blockIdx.x;         // 0..16383
    const int xcd = b & 7;              // HW round-robins blocks across 8 XCDs
    const int n   = ((b >> 3) << 8) + threadIdx.x;

    // NT loads: pos is streamed, keep it out of L2 (tables own the L2)
    const float p0 = __builtin_nontemporal_load(pos + 3 * n + 0);
    const float p1 = __builtin_nontemporal_load(pos + 3 * n + 1);
    const float p2 = __builtin_nontemporal_load(pos + 3 * n + 2);

    float w[2][4];
    int   hidx[2][4];

    #pragma unroll
    for (int t = 0; t < 2; ++t) {
        const int level = xcd + (t << 3);
        const float s = sc.s[level];
        int rem0[4], rank[4];
        permuto_point(p0 * s, p1 * s, p2 * s, rem0, rank, w[t]);
        #pragma unroll
        for (int k = 0; k < 4; ++k) {
            int h = 0;
            #pragma unroll
            for (int i = 0; i < 3; ++i) {
                const int key = rem0[i] + k - 4 * (rank[i] > 3 - k);
                h = (int)((unsigned)(h + key) * kHashMult);
            }
            hidx[t][k] = (level << kCapLog2) + (h & kCapMask);
        }
    }

    // All 8 gathers issued back-to-back: full MLP before the first waitcnt.
    unsigned e[2][4];
    #pragma unroll
    for (int t = 0; t < 2; ++t)
        #pragma unroll
        for (int k = 0; k < 4; ++k)
            e[t][k] = tab[hidx[t][k]];

    #pragma unroll
    for (int t = 0; t < 2; ++t) {
        float o0 = 0.0f, o1 = 0.0f;
        #pragma unroll
        for (int k = 0; k < 4; ++k) {
            const __half2 hv = *reinterpret_cast<const __half2*>(&e[t][k]);
            o0 += w[t][k] * __low2float(hv);
            o1 += w[t][k] * __high2float(hv);
        }
        vf2 o; o.x = o0; o.y = o1;
        const int level = xcd + (t << 3);
        __builtin_nontemporal_store(o, out_t + ((size_t)level << kCapLog2) + n);
    }
}

// ---------------- kernel 3: [level][point] -> [point][level] transpose -----
__global__ __launch_bounds__(256) void transpose_out(
    const vf2* __restrict__ out_t, vf4* __restrict__ out4)
{
    __shared__ float tile[256][36];     // 36-float row: 16B-aligned float4 reads, ~2-way banks
    const int t  = threadIdx.x;
    const int p0 = blockIdx.x * 256;

    #pragma unroll
    for (int l = 0; l < kL; ++l) {
        vf2 v = __builtin_nontemporal_load(out_t + ((size_t)l << kCapLog2) + p0 + t);
        tile[t][2 * l + 0] = v.x;
        tile[t][2 * l + 1] = v.y;
    }
    __syncthreads();

    const size_t base = (size_t)p0 * 8;           // float4 index of block's output
    #pragma unroll
    for (int i = 0; i < 8; ++i) {
        const int idx = i * 256 + t;              // 0..2047 float4s = 256 pts * 32 floats
        const int p = idx >> 3, q = idx & 7;
        vf4 v = *reinterpret_cast<const vf4*>(&tile[p][4 * q]);
        out4[base + idx] = v;
    }
}

// ---------------- fallback (R1 kernel) if ws is too small ------------------
__global__ __launch_bounds__(256) void permuto_fwd(
    const float* __restrict__ pos,
    const float* __restrict__ params,
    float* __restrict__ out,
    ScaleArr sc)
{
    const int gid = blockIdx.x * 256 + threadIdx.x;
    const int l = gid & (kL - 1);
    const int n = gid >> 4;

    const float s  = sc.s[l];
    const float x0 = pos[3 * n + 0] * s;
    const float x1 = pos[3 * n + 1] * s;
    const float x2 = pos[3 * n + 2] * s;

    int rem0[4], rank[4];
    float w[4];
    permuto_point(x0, x1, x2, rem0, rank, w);

    const float2* __restrict__ tab = (const float2*)params + ((size_t)l << kCapLog2);
    float o0 = 0.0f, o1 = 0.0f;
    #pragma unroll
    for (int k = 0; k < 4; ++k) {
        int h = 0;
        #pragma unroll
        for (int i = 0; i < 3; ++i) {
            const int key = rem0[i] + k - 4 * (rank[i] > 3 - k);
            h = (int)((unsigned)(h + key) * kHashMult);
        }
        const float2 f = tab[h & kCapMask];
        o0 += w[k] * f.x;
        o1 += w[k] * f.y;
    }
    ((float2*)out)[(n << 4) + l] = make_float2(o0, o1);
}

} // namespace

extern "C" void kernel_launch(void* const* d_in, const int* in_sizes, int n_in,
                              void* d_out, int out_size, void* d_ws, size_t ws_size,
                              hipStream_t stream) {
    const float* pos    = (const float*)d_in[0];
    const float* params = (const float*)d_in[1];
    float* out          = (float*)d_out;

    ScaleArr sc;
    for (int l = 0; l < kL; ++l)
        sc.s[l] = (float)(16.0 * pow(128.0, (double)l / 15.0));

    const size_t tab_bytes  = (size_t)kL * kCap * 4;   // fp16 table: 32 MiB
    const size_t outt_bytes = (size_t)kL * kN * 8;     // level-major out: 64 MiB

    if (ws_size >= tab_bytes + outt_bytes) {
        unsigned* tab = (unsigned*)d_ws;
        vf2* out_t    = (vf2*)((char*)d_ws + tab_bytes);

        conv_tab<<<(kL * kCap * 2 / 4) / 256, 256, 0, stream>>>(params, tab);
        // 8 XCD-pairs * 2048 point-chunks
        permuto_main2<<<(kN / 256) * 8, 256, 0, stream>>>(pos, tab, out_t, sc);
        transpose_out<<<kN / 256, 256, 0, stream>>>(out_t, (vf4*)out);
    } else {
        permuto_fwd<<<(kN * kL) / 256, 256, 0, stream>>>(pos, params, out, sc);
    }
}

// Round 4
// 186.255 us; speedup vs baseline: 1.1080x; 1.1080x over previous
//
#include <hip/hip_runtime.h>
#include <hip/hip_fp16.h>
#include <cmath>

namespace {

typedef float    vf4 __attribute__((ext_vector_type(4)));
typedef unsigned uv2 __attribute__((ext_vector_type(2)));

constexpr int kN = 524288;
constexpr int kL = 16;
constexpr int kCapLog2 = 19;
constexpr int kCap = 1 << kCapLog2;
constexpr int kCapMask = kCap - 1;
constexpr unsigned kHashMult = 2531011u;

// Dense key-box geometry for levels 0..3 (keys = rem0[i] + k - 4b, rem0 in 4Z,
// bounds from elev ranges at s = {16, 22.1106, 30.5550, 42.2243} with margin).
constexpr int cD[4][3]   = {{ 8, 8, 6},{10,10, 9},{13,12,10},{17,16,14}};
constexpr int cB[4][3]   = {{-4,-16,-16},{-4,-20,-24},{-4,-24,-28},{-4,-32,-40}};
constexpr int cCnt[4]    = {1536, 3600, 6240, 15232};           // 4*d0*d1*d2
constexpr int cOff[4]    = {0, 1536, 5136, 11376};              // prefix
constexpr int kLdsCnt    = 11376;                               // levels 0..2
constexpr int kDenseCnt  = 26608;                               // levels 0..3

struct ScaleArr { float s[kL]; };

// ---------------- shared per-thread math (identical numerics to R1) --------
__device__ __forceinline__ void permuto_point(
    float x0, float x1, float x2, int rem0[4], int rank[4], float w[4])
{
    const float E00 = (float)( 0.70710678118654752440);
    const float E01 = (float)( 0.40824829046386301637);
    const float E02 = (float)( 0.28867513459481288225);
    const float E10 = (float)(-0.70710678118654752440);
    const float E21 = (float)(-2.0 * 0.40824829046386301637);
    const float E32 = (float)(-3.0 * 0.28867513459481288225);

    float elev[4];
    elev[0] = E00 * x0 + E01 * x1 + E02 * x2;
    elev[1] = E10 * x0 + E01 * x1 + E02 * x2;
    elev[2] =            E21 * x1 + E02 * x2;
    elev[3] =                       E32 * x2;

    float rem0f[4], di[4];
    #pragma unroll
    for (int v = 0; v < 4; ++v) {
        rem0f[v] = rintf(elev[v] * 0.25f) * 4.0f;
        di[v]    = elev[v] - rem0f[v];
    }
    const int sums = (int)((((rem0f[0] + rem0f[1]) + rem0f[2]) + rem0f[3]) * 0.25f);

    #pragma unroll
    for (int a = 0; a < 4; ++a) {
        int r = 0;
        #pragma unroll
        for (int b = 0; b < 4; ++b)
            r += (di[b] > di[a]) || (di[b] == di[a] && b < a);
        rank[a] = r + sums;
        rem0[a] = (int)rem0f[a];
    }
    #pragma unroll
    for (int v = 0; v < 4; ++v) {
        if (rank[v] < 0)      { rank[v] += 4; rem0[v] += 4; }
        else if (rank[v] > 3) { rank[v] -= 4; rem0[v] -= 4; }
    }

    float dbr[4];
    #pragma unroll
    for (int v = 0; v < 4; ++v)
        dbr[rank[v] & 3] = (elev[v] - (float)rem0[v]) * 0.25f;

    w[0] = (1.0f + dbr[3]) - dbr[0];
    w[1] = dbr[2] - dbr[3];
    w[2] = dbr[1] - dbr[2];
    w[3] = dbr[0] - dbr[1];
}

// ---------------- kernel 1: f32 params -> fp16 table in ws -----------------
__global__ __launch_bounds__(256) void conv_tab(const float* __restrict__ params,
                                                unsigned* __restrict__ tab)
{
    const int i = blockIdx.x * 256 + threadIdx.x;
    vf4 v = __builtin_nontemporal_load((const vf4*)params + i);
    __half2 a = __floats2half2_rn(v.x, v.y);
    __half2 b = __floats2half2_rn(v.z, v.w);
    uv2 o;
    o.x = *reinterpret_cast<unsigned*>(&a);
    o.y = *reinterpret_cast<unsigned*>(&b);
    __builtin_nontemporal_store(o, (uv2*)tab + i);
}

// -------- kernel 2: materialize dense key-box tables for levels 0..3 -------
__global__ __launch_bounds__(256) void build_dense(const float* __restrict__ params,
                                                   unsigned* __restrict__ dense)
{
    const int e = blockIdx.x * 256 + threadIdx.x;
    if (e >= kDenseCnt) return;
    int l, r;
    if      (e < cOff[1]) { l = 0; r = e; }
    else if (e < cOff[2]) { l = 1; r = e - cOff[1]; }
    else if (e < cOff[3]) { l = 2; r = e - cOff[2]; }
    else                  { l = 3; r = e - cOff[3]; }
    const int d0 = cD[l][0], d1 = cD[l][1], d2 = cD[l][2];
    const int per = d0 * d1 * d2;
    const int k  = r / per;  r -= k * per;
    const int i0 = r / (d1 * d2); r -= i0 * (d1 * d2);
    const int i1 = r / d2;
    const int i2 = r - i1 * d2;

    const int key0 = cB[l][0] + 4 * i0 + k;
    const int key1 = cB[l][1] + 4 * i1 + k;
    const int key2 = cB[l][2] + 4 * i2 + k;
    int h = 0;
    h = (int)((unsigned)(h + key0) * kHashMult);
    h = (int)((unsigned)(h + key1) * kHashMult);
    h = (int)((unsigned)(h + key2) * kHashMult);
    const size_t entry = ((size_t)l << kCapLog2) + (h & kCapMask);
    const __half2 hv = __floats2half2_rn(params[entry * 2], params[entry * 2 + 1]);
    dense[e] = *reinterpret_cast<const unsigned*>(&hv);
}

// -------- kernel 3: coarse levels 0..2 from LDS, level 3 from L1/L2 --------
__global__ __launch_bounds__(256) void permuto_coarse(
    const float* __restrict__ pos,
    const unsigned* __restrict__ dense,
    unsigned* __restrict__ out_t16,
    ScaleArr sc)
{
    __shared__ unsigned sd[kLdsCnt];   // 44.4 KB -> 3 blocks/CU
    for (int i = threadIdx.x; i < kLdsCnt; i += 256)
        sd[i] = dense[i];
    __syncthreads();

    const int n = blockIdx.x * 256 + threadIdx.x;
    const float p0 = __builtin_nontemporal_load(pos + 3 * n + 0);
    const float p1 = __builtin_nontemporal_load(pos + 3 * n + 1);
    const float p2 = __builtin_nontemporal_load(pos + 3 * n + 2);
    const unsigned* __restrict__ denseL3 = dense + cOff[3];

    #pragma unroll
    for (int l = 0; l < 4; ++l) {
        const float s = sc.s[l];
        int rem0[4], rank[4];
        float w[4];
        permuto_point(p0 * s, p1 * s, p2 * s, rem0, rank, w);

        unsigned ev[4];
        #pragma unroll
        for (int k = 0; k < 4; ++k) {
            const int i0 = (rem0[0] - 4 * (rank[0] > 3 - k) - cB[l][0]) >> 2;
            const int i1 = (rem0[1] - 4 * (rank[1] > 3 - k) - cB[l][1]) >> 2;
            const int i2 = (rem0[2] - 4 * (rank[2] > 3 - k) - cB[l][2]) >> 2;
            const int idx = ((k * cD[l][0] + i0) * cD[l][1] + i1) * cD[l][2] + i2;
            ev[k] = (l < 3) ? sd[cOff[l] + idx] : denseL3[idx];
        }
        float o0 = 0.0f, o1 = 0.0f;
        #pragma unroll
        for (int k = 0; k < 4; ++k) {
            const __half2 hv = *reinterpret_cast<const __half2*>(&ev[k]);
            o0 += w[k] * __low2float(hv);
            o1 += w[k] * __high2float(hv);
        }
        const __half2 po = __floats2half2_rn(o0, o1);
        __builtin_nontemporal_store(*reinterpret_cast<const unsigned*>(&po),
                                    out_t16 + ((size_t)l << kCapLog2) + n);
    }
}

// -------- kernel 4: fine levels 4..15, XCD<->level L2 affinity -------------
__global__ __launch_bounds__(256) void permuto_fine(
    const float* __restrict__ pos,
    const unsigned* __restrict__ tab,
    unsigned* __restrict__ out_t16,
    ScaleArr sc)
{
    const int b   = blockIdx.x;
    const int xcd = b & 7;
    const int j   = b >> 3;            // 0..3071
    int level, n;
    if (j < 2048) {                    // levels 4..11: one table per XCD
        level = 4 + xcd;
        n = (j << 8) + threadIdx.x;
    } else {                           // levels 12..15: each on 2 XCDs
        level = 12 + (xcd & 3);
        const int c = ((j - 2048) << 1) | (xcd >> 2);
        n = (c << 8) + threadIdx.x;
    }

    const float s  = sc.s[level];
    const float x0 = __builtin_nontemporal_load(pos + 3 * n + 0) * s;
    const float x1 = __builtin_nontemporal_load(pos + 3 * n + 1) * s;
    const float x2 = __builtin_nontemporal_load(pos + 3 * n + 2) * s;

    int rem0[4], rank[4];
    float w[4];
    permuto_point(x0, x1, x2, rem0, rank, w);

    const unsigned* __restrict__ t = tab + ((size_t)level << kCapLog2);
    int hidx[4];
    #pragma unroll
    for (int k = 0; k < 4; ++k) {
        int h = 0;
        #pragma unroll
        for (int i = 0; i < 3; ++i) {
            const int key = rem0[i] + k - 4 * (rank[i] > 3 - k);
            h = (int)((unsigned)(h + key) * kHashMult);
        }
        hidx[k] = h & kCapMask;
    }
    unsigned e[4];
    #pragma unroll
    for (int k = 0; k < 4; ++k) e[k] = t[hidx[k]];

    float o0 = 0.0f, o1 = 0.0f;
    #pragma unroll
    for (int k = 0; k < 4; ++k) {
        const __half2 hv = *reinterpret_cast<const __half2*>(&e[k]);
        o0 += w[k] * __low2float(hv);
        o1 += w[k] * __high2float(hv);
    }
    const __half2 po = __floats2half2_rn(o0, o1);
    __builtin_nontemporal_store(*reinterpret_cast<const unsigned*>(&po),
                                out_t16 + ((size_t)level << kCapLog2) + n);
}

// -------- kernel 5: [level][point] fp16 -> [point][32 floats] --------------
__global__ __launch_bounds__(256) void transpose_out16(
    const unsigned* __restrict__ out_t16, vf4* __restrict__ out4)
{
    __shared__ float tile[256][36];
    const int t  = threadIdx.x;
    const int p0 = blockIdx.x * 256;

    #pragma unroll
    for (int l = 0; l < kL; ++l) {
        const unsigned u = __builtin_nontemporal_load(out_t16 + ((size_t)l << kCapLog2) + p0 + t);
        const __half2 hv = *reinterpret_cast<const __half2*>(&u);
        tile[t][2 * l + 0] = __low2float(hv);
        tile[t][2 * l + 1] = __high2float(hv);
    }
    __syncthreads();

    const size_t base = (size_t)p0 * 8;
    #pragma unroll
    for (int i = 0; i < 8; ++i) {
        const int idx = i * 256 + t;
        const int p = idx >> 3, q = idx & 7;
        vf4 v = *reinterpret_cast<const vf4*>(&tile[p][4 * q]);
        out4[base + idx] = v;
    }
}

// ---------------- fallback (R1 kernel) if ws is too small ------------------
__global__ __launch_bounds__(256) void permuto_fwd(
    const float* __restrict__ pos,
    const float* __restrict__ params,
    float* __restrict__ out,
    ScaleArr sc)
{
    const int gid = blockIdx.x * 256 + threadIdx.x;
    const int l = gid & (kL - 1);
    const int n = gid >> 4;

    const float s  = sc.s[l];
    const float x0 = pos[3 * n + 0] * s;
    const float x1 = pos[3 * n + 1] * s;
    const float x2 = pos[3 * n + 2] * s;

    int rem0[4], rank[4];
    float w[4];
    permuto_point(x0, x1, x2, rem0, rank, w);

    const float2* __restrict__ tab = (const float2*)params + ((size_t)l << kCapLog2);
    float o0 = 0.0f, o1 = 0.0f;
    #pragma unroll
    for (int k = 0; k < 4; ++k) {
        int h = 0;
        #pragma unroll
        for (int i = 0; i < 3; ++i) {
            const int key = rem0[i] + k - 4 * (rank[i] > 3 - k);
            h = (int)((unsigned)(h + key) * kHashMult);
        }
        const float2 f = tab[h & kCapMask];
        o0 += w[k] * f.x;
        o1 += w[k] * f.y;
    }
    ((float2*)out)[(n << 4) + l] = make_float2(o0, o1);
}

} // namespace

extern "C" void kernel_launch(void* const* d_in, const int* in_sizes, int n_in,
                              void* d_out, int out_size, void* d_ws, size_t ws_size,
                              hipStream_t stream) {
    const float* pos    = (const float*)d_in[0];
    const float* params = (const float*)d_in[1];
    float* out          = (float*)d_out;

    ScaleArr sc;
    for (int l = 0; l < kL; ++l)
        sc.s[l] = (float)(16.0 * pow(128.0, (double)l / 15.0));

    const size_t tab_bytes   = (size_t)kL * kCap * 4;   // fp16 table: 32 MiB
    const size_t outt_bytes  = (size_t)kL * kN * 4;     // fp16 level-major out: 32 MiB
    const size_t dense_bytes = (size_t)kDenseCnt * 4;   // ~104 KiB

    if (ws_size >= tab_bytes + outt_bytes + dense_bytes) {
        unsigned* tab     = (unsigned*)d_ws;
        unsigned* out_t16 = (unsigned*)((char*)d_ws + tab_bytes);
        unsigned* dense   = (unsigned*)((char*)d_ws + tab_bytes + outt_bytes);

        conv_tab<<<(kL * kCap * 2 / 4) / 256, 256, 0, stream>>>(params, tab);
        build_dense<<<(kDenseCnt + 255) / 256, 256, 0, stream>>>(params, dense);
        permuto_coarse<<<kN / 256, 256, 0, stream>>>(pos, dense, out_t16, sc);
        permuto_fine<<<8 * 3072, 256, 0, stream>>>(pos, tab, out_t16, sc);
        transpose_out16<<<kN / 256, 256, 0, stream>>>(out_t16, (vf4*)out);
    } else {
        permuto_fwd<<<(kN * kL) / 256, 256, 0, stream>>>(pos, params, out, sc);
    }
}

// Round 5
// 175.071 us; speedup vs baseline: 1.1788x; 1.0639x over previous
//
#include <hip/hip_runtime.h>
#include <hip/hip_fp16.h>
#include <cmath>

namespace {

typedef float    vf4 __attribute__((ext_vector_type(4)));
typedef unsigned uv2 __attribute__((ext_vector_type(2)));

constexpr int kN = 524288;
constexpr int kL = 16;
constexpr int kCapLog2 = 19;
constexpr int kCap = 1 << kCapLog2;
constexpr int kCapMask = kCap - 1;
constexpr unsigned kHashMult = 2531011u;

// Dense key-box geometry for levels 0..3.
constexpr int cD[4][3]   = {{ 8, 8, 6},{10,10, 9},{13,12,10},{17,16,14}};
constexpr int cB[4][3]   = {{-4,-16,-16},{-4,-20,-24},{-4,-24,-28},{-4,-32,-40}};
constexpr int cOff[4]    = {0, 1536, 5136, 11376};
constexpr int kLdsCnt    = 11376;    // levels 0..2 (44.4 KB LDS)
constexpr int kDenseCnt  = 26608;    // levels 0..3

// mega1 geometry: fine456 (3*2048) : conv 7-15 (9216) interleaved 2:3, + build
constexpr int kMegaMain  = 15360;    // 5 * 3072
constexpr int kBuildBlks = 104;      // ceil(26608/256)
constexpr int kConvBaseF4 = 7 * (kCap * 2 / 4);   // float4 offset of level-7 params

struct ScaleArr { float s[kL]; };

// ---------------- shared per-thread math (identical numerics since R1) -----
__device__ __forceinline__ void permuto_point(
    float x0, float x1, float x2, int rem0[4], int rank[4], float w[4])
{
    const float E00 = (float)( 0.70710678118654752440);
    const float E01 = (float)( 0.40824829046386301637);
    const float E02 = (float)( 0.28867513459481288225);
    const float E10 = (float)(-0.70710678118654752440);
    const float E21 = (float)(-2.0 * 0.40824829046386301637);
    const float E32 = (float)(-3.0 * 0.28867513459481288225);

    float elev[4];
    elev[0] = E00 * x0 + E01 * x1 + E02 * x2;
    elev[1] = E10 * x0 + E01 * x1 + E02 * x2;
    elev[2] =            E21 * x1 + E02 * x2;
    elev[3] =                       E32 * x2;

    float rem0f[4], di[4];
    #pragma unroll
    for (int v = 0; v < 4; ++v) {
        rem0f[v] = rintf(elev[v] * 0.25f) * 4.0f;
        di[v]    = elev[v] - rem0f[v];
    }
    const int sums = (int)((((rem0f[0] + rem0f[1]) + rem0f[2]) + rem0f[3]) * 0.25f);

    #pragma unroll
    for (int a = 0; a < 4; ++a) {
        int r = 0;
        #pragma unroll
        for (int b = 0; b < 4; ++b)
            r += (di[b] > di[a]) || (di[b] == di[a] && b < a);
        rank[a] = r + sums;
        rem0[a] = (int)rem0f[a];
    }
    #pragma unroll
    for (int v = 0; v < 4; ++v) {
        if (rank[v] < 0)      { rank[v] += 4; rem0[v] += 4; }
        else if (rank[v] > 3) { rank[v] -= 4; rem0[v] -= 4; }
    }

    float dbr[4];
    #pragma unroll
    for (int v = 0; v < 4; ++v)
        dbr[rank[v] & 3] = (elev[v] - (float)rem0[v]) * 0.25f;

    w[0] = (1.0f + dbr[3]) - dbr[0];
    w[1] = dbr[2] - dbr[3];
    w[2] = dbr[1] - dbr[2];
    w[3] = dbr[0] - dbr[1];
}

// ---- K1 mega: fine levels 4-6 (direct f32) ∥ conv 7-15 ∥ build_dense ------
__global__ __launch_bounds__(256) void mega1(
    const float* __restrict__ pos,
    const float* __restrict__ params,
    unsigned* __restrict__ tab,
    unsigned* __restrict__ out_t16,
    unsigned* __restrict__ dense,
    ScaleArr sc)
{
    const int b = blockIdx.x;
    if (b < kMegaMain) {
        const int q = b / 5, r = b % 5;
        if (r < 2) {
            // ---- fine levels 4..6, f32 gathers straight from params.
            // Accessed footprint = dense-box image: 0.3+0.8+2.2 MB — fits
            // every XCD L2, so no XCD pinning needed.
            const int idx   = q * 2 + r;            // 0..6143
            const int level = 4 + (idx >> 11);
            const int n     = ((idx & 2047) << 8) + threadIdx.x;

            const float s  = sc.s[level];
            const float x0 = __builtin_nontemporal_load(pos + 3 * n + 0) * s;
            const float x1 = __builtin_nontemporal_load(pos + 3 * n + 1) * s;
            const float x2 = __builtin_nontemporal_load(pos + 3 * n + 2) * s;

            int rem0[4], rank[4];
            float w[4];
            permuto_point(x0, x1, x2, rem0, rank, w);

            const float2* __restrict__ t2 =
                (const float2*)params + ((size_t)level << kCapLog2);
            int hidx[4];
            #pragma unroll
            for (int k = 0; k < 4; ++k) {
                int h = 0;
                #pragma unroll
                for (int i = 0; i < 3; ++i) {
                    const int key = rem0[i] + k - 4 * (rank[i] > 3 - k);
                    h = (int)((unsigned)(h + key) * kHashMult);
                }
                hidx[k] = h & kCapMask;
            }
            float2 f[4];
            #pragma unroll
            for (int k = 0; k < 4; ++k) f[k] = t2[hidx[k]];

            float o0 = 0.0f, o1 = 0.0f;
            #pragma unroll
            for (int k = 0; k < 4; ++k) { o0 += w[k] * f[k].x; o1 += w[k] * f[k].y; }

            const __half2 po = __floats2half2_rn(o0, o1);
            __builtin_nontemporal_store(*reinterpret_cast<const unsigned*>(&po),
                                        out_t16 + ((size_t)level << kCapLog2) + n);
        } else {
            // ---- conv: f32 params -> fp16 tab, levels 7..15 only
            const int i  = q * 3 + (r - 2);         // 0..9215
            const int jj = kConvBaseF4 + i * 256 + threadIdx.x;
            vf4 v = __builtin_nontemporal_load((const vf4*)params + jj);
            __half2 a = __floats2half2_rn(v.x, v.y);
            __half2 c = __floats2half2_rn(v.z, v.w);
            uv2 o;
            o.x = *reinterpret_cast<unsigned*>(&a);
            o.y = *reinterpret_cast<unsigned*>(&c);
            __builtin_nontemporal_store(o, (uv2*)tab + jj);
        }
    } else {
        // ---- build dense key-box tables for levels 0..3
        const int e = (b - kMegaMain) * 256 + threadIdx.x;
        if (e >= kDenseCnt) return;
        int l, r;
        if      (e < cOff[1]) { l = 0; r = e; }
        else if (e < cOff[2]) { l = 1; r = e - cOff[1]; }
        else if (e < cOff[3]) { l = 2; r = e - cOff[2]; }
        else                  { l = 3; r = e - cOff[3]; }
        const int d0 = cD[l][0], d1 = cD[l][1], d2 = cD[l][2];
        const int per = d0 * d1 * d2;
        int rr = r;
        const int k  = rr / per;  rr -= k * per;
        const int i0 = rr / (d1 * d2); rr -= i0 * (d1 * d2);
        const int i1 = rr / d2;
        const int i2 = rr - i1 * d2;

        const int key0 = cB[l][0] + 4 * i0 + k;
        const int key1 = cB[l][1] + 4 * i1 + k;
        const int key2 = cB[l][2] + 4 * i2 + k;
        int h = 0;
        h = (int)((unsigned)(h + key0) * kHashMult);
        h = (int)((unsigned)(h + key1) * kHashMult);
        h = (int)((unsigned)(h + key2) * kHashMult);
        const size_t entry = ((size_t)l << kCapLog2) + (h & kCapMask);
        const __half2 hv = __floats2half2_rn(params[entry * 2], params[entry * 2 + 1]);
        dense[e] = *reinterpret_cast<const unsigned*>(&hv);
    }
}

// ---- K2: fine levels 7..15. XCD x owns level 7+x; level 15 split 1/8 ------
__global__ __launch_bounds__(256) void fine715(
    const float* __restrict__ pos,
    const unsigned* __restrict__ tab,
    unsigned* __restrict__ out_t16,
    ScaleArr sc)
{
    const int b   = blockIdx.x;
    const int xcd = b & 7;
    const int j   = b >> 3;             // 0..2303
    int level, n;
    if (j < 2048) {                     // primary: levels 7..14
        level = 7 + xcd;
        n = (j << 8) + threadIdx.x;
    } else {                            // tail: level 15, 1/8 of points per XCD
        level = 15;
        const int c = (j - 2048) + (xcd << 8);
        n = (c << 8) + threadIdx.x;
    }

    const float s  = sc.s[level];
    const float x0 = __builtin_nontemporal_load(pos + 3 * n + 0) * s;
    const float x1 = __builtin_nontemporal_load(pos + 3 * n + 1) * s;
    const float x2 = __builtin_nontemporal_load(pos + 3 * n + 2) * s;

    int rem0[4], rank[4];
    float w[4];
    permuto_point(x0, x1, x2, rem0, rank, w);

    const unsigned* __restrict__ t = tab + ((size_t)level << kCapLog2);
    int hidx[4];
    #pragma unroll
    for (int k = 0; k < 4; ++k) {
        int h = 0;
        #pragma unroll
        for (int i = 0; i < 3; ++i) {
            const int key = rem0[i] + k - 4 * (rank[i] > 3 - k);
            h = (int)((unsigned)(h + key) * kHashMult);
        }
        hidx[k] = h & kCapMask;
    }
    unsigned e[4];
    #pragma unroll
    for (int k = 0; k < 4; ++k) e[k] = t[hidx[k]];

    float o0 = 0.0f, o1 = 0.0f;
    #pragma unroll
    for (int k = 0; k < 4; ++k) {
        const __half2 hv = *reinterpret_cast<const __half2*>(&e[k]);
        o0 += w[k] * __low2float(hv);
        o1 += w[k] * __high2float(hv);
    }
    const __half2 po = __floats2half2_rn(o0, o1);
    __builtin_nontemporal_store(*reinterpret_cast<const unsigned*>(&po),
                                out_t16 + ((size_t)level << kCapLog2) + n);
}

// ---- K2b: coarse levels 0..2 from LDS, level 3 from L1/L2 -----------------
__global__ __launch_bounds__(256) void permuto_coarse(
    const float* __restrict__ pos,
    const unsigned* __restrict__ dense,
    unsigned* __restrict__ out_t16,
    ScaleArr sc)
{
    __shared__ unsigned sd[kLdsCnt];
    for (int i = threadIdx.x; i < kLdsCnt; i += 256)
        sd[i] = dense[i];
    __syncthreads();

    const int n = blockIdx.x * 256 + threadIdx.x;
    const float p0 = __builtin_nontemporal_load(pos + 3 * n + 0);
    const float p1 = __builtin_nontemporal_load(pos + 3 * n + 1);
    const float p2 = __builtin_nontemporal_load(pos + 3 * n + 2);
    const unsigned* __restrict__ denseL3 = dense + cOff[3];

    #pragma unroll
    for (int l = 0; l < 4; ++l) {
        const float s = sc.s[l];
        int rem0[4], rank[4];
        float w[4];
        permuto_point(p0 * s, p1 * s, p2 * s, rem0, rank, w);

        unsigned ev[4];
        #pragma unroll
        for (int k = 0; k < 4; ++k) {
            const int i0 = (rem0[0] - 4 * (rank[0] > 3 - k) - cB[l][0]) >> 2;
            const int i1 = (rem0[1] - 4 * (rank[1] > 3 - k) - cB[l][1]) >> 2;
            const int i2 = (rem0[2] - 4 * (rank[2] > 3 - k) - cB[l][2]) >> 2;
            const int idx = ((k * cD[l][0] + i0) * cD[l][1] + i1) * cD[l][2] + i2;
            ev[k] = (l < 3) ? sd[cOff[l] + idx] : denseL3[idx];
        }
        float o0 = 0.0f, o1 = 0.0f;
        #pragma unroll
        for (int k = 0; k < 4; ++k) {
            const __half2 hv = *reinterpret_cast<const __half2*>(&ev[k]);
            o0 += w[k] * __low2float(hv);
            o1 += w[k] * __high2float(hv);
        }
        const __half2 po = __floats2half2_rn(o0, o1);
        __builtin_nontemporal_store(*reinterpret_cast<const unsigned*>(&po),
                                    out_t16 + ((size_t)l << kCapLog2) + n);
    }
}

// ---- K3: [level][point] fp16 -> [point][32 floats] ------------------------
__global__ __launch_bounds__(256) void transpose_out16(
    const unsigned* __restrict__ out_t16, vf4* __restrict__ out4)
{
    __shared__ float tile[256][36];
    const int t  = threadIdx.x;
    const int p0 = blockIdx.x * 256;

    #pragma unroll
    for (int l = 0; l < kL; ++l) {
        const unsigned u = __builtin_nontemporal_load(out_t16 + ((size_t)l << kCapLog2) + p0 + t);
        const __half2 hv = *reinterpret_cast<const __half2*>(&u);
        tile[t][2 * l + 0] = __low2float(hv);
        tile[t][2 * l + 1] = __high2float(hv);
    }
    __syncthreads();

    const size_t base = (size_t)p0 * 8;
    #pragma unroll
    for (int i = 0; i < 8; ++i) {
        const int idx = i * 256 + t;
        const int p = idx >> 3, q = idx & 7;
        vf4 v = *reinterpret_cast<const vf4*>(&tile[p][4 * q]);
        out4[base + idx] = v;
    }
}

// ---------------- fallback (R1 kernel) if ws is too small ------------------
__global__ __launch_bounds__(256) void permuto_fwd(
    const float* __restrict__ pos,
    const float* __restrict__ params,
    float* __restrict__ out,
    ScaleArr sc)
{
    const int gid = blockIdx.x * 256 + threadIdx.x;
    const int l = gid & (kL - 1);
    const int n = gid >> 4;

    const float s  = sc.s[l];
    const float x0 = pos[3 * n + 0] * s;
    const float x1 = pos[3 * n + 1] * s;
    const float x2 = pos[3 * n + 2] * s;

    int rem0[4], rank[4];
    float w[4];
    permuto_point(x0, x1, x2, rem0, rank, w);

    const float2* __restrict__ tab = (const float2*)params + ((size_t)l << kCapLog2);
    float o0 = 0.0f, o1 = 0.0f;
    #pragma unroll
    for (int k = 0; k < 4; ++k) {
        int h = 0;
        #pragma unroll
        for (int i = 0; i < 3; ++i) {
            const int key = rem0[i] + k - 4 * (rank[i] > 3 - k);
            h = (int)((unsigned)(h + key) * kHashMult);
        }
        const float2 f = tab[h & kCapMask];
        o0 += w[k] * f.x;
        o1 += w[k] * f.y;
    }
    ((float2*)out)[(n << 4) + l] = make_float2(o0, o1);
}

} // namespace

extern "C" void kernel_launch(void* const* d_in, const int* in_sizes, int n_in,
                              void* d_out, int out_size, void* d_ws, size_t ws_size,
                              hipStream_t stream) {
    const float* pos    = (const float*)d_in[0];
    const float* params = (const float*)d_in[1];
    float* out          = (float*)d_out;

    ScaleArr sc;
    for (int l = 0; l < kL; ++l)
        sc.s[l] = (float)(16.0 * pow(128.0, (double)l / 15.0));

    const size_t tab_bytes   = (size_t)kL * kCap * 4;   // fp16 table: 32 MiB
    const size_t outt_bytes  = (size_t)kL * kN * 4;     // fp16 level-major out: 32 MiB
    const size_t dense_bytes = (size_t)kDenseCnt * 4;   // ~104 KiB

    if (ws_size >= tab_bytes + outt_bytes + dense_bytes) {
        unsigned* tab     = (unsigned*)d_ws;
        unsigned* out_t16 = (unsigned*)((char*)d_ws + tab_bytes);
        unsigned* dense   = (unsigned*)((char*)d_ws + tab_bytes + outt_bytes);

        mega1<<<kMegaMain + kBuildBlks, 256, 0, stream>>>(pos, params, tab, out_t16, dense, sc);
        fine715<<<8 * 2304, 256, 0, stream>>>(pos, tab, out_t16, sc);
        permuto_coarse<<<kN / 256, 256, 0, stream>>>(pos, dense, out_t16, sc);
        transpose_out16<<<kN / 256, 256, 0, stream>>>(out_t16, (vf4*)out);
    } else {
        permuto_fwd<<<(kN * kL) / 256, 256, 0, stream>>>(pos, params, out, sc);
    }
}